// Round 3
// baseline (213.639 us; speedup 1.0000x reference)
//
#include <hip/hip_runtime.h>

#define NN 50000     // nodes
#define NE 600000    // directed edges (self loops handled separately)
#define NG 64        // graphs
#define DIM 128      // feature dim (D == H == 128)
#define NCLS 10
#define NNP 50176    // 224*224 (padded K for pool GEMM)
#define KBLK 392     // split-K blocks for pool GEMM (KCH = 128 = 4 MFMA K-steps)
#define KCH 128      // K-chunk per block (KBLK*KCH == NNP)
#define CAP 64       // ELL row capacity (multinomial max deg ~33; 64 is safe)
#define FILLB 1172   // ceil(NE/512) edge blocks, 2 edges/thread
#define GEMMB 782    // ceil(NN/64)
#define PAIR (GEMMB * 2)          // 1564 (fill/gemm interleave range)
#define TZB 784      // T-zero blocks
#define IPAIR (TZB * 2)           // 1568 (Tzero/deg interleave range)
#define BSW_TAIL_START ((size_t)(NN >> 5) * 4096)   // ushort idx of t32=1562 block

typedef unsigned short ushort;
typedef unsigned char uchar;
typedef __attribute__((ext_vector_type(8))) short short8;   // 8 bf16 (4 VGPRs)
typedef __attribute__((ext_vector_type(4))) float float4v;  // 4 fp32 acc
typedef __attribute__((ext_vector_type(2))) float float2v;

__device__ __forceinline__ ushort f2bf(float f) {
    unsigned u = __float_as_uint(f);
    u += 0x7fff + ((u >> 16) & 1);          // RNE
    return (ushort)(u >> 16);
}
// fp8 e4m3 (OCP) encode via HW cvt (RNE, satfinite)
__device__ __forceinline__ uchar f2fp8(float f) {
    int p = __builtin_amdgcn_cvt_pk_fp8_f32(f, f, 0, false);
    return (uchar)(p & 0xff);
}
// decode 8 fp8 (uint2) -> accumulate into a[0..7]
__device__ __forceinline__ void accfp8(float* a, uint2 v) {
    float2v p0 = __builtin_amdgcn_cvt_pk_f32_fp8(v.x, false);
    float2v p1 = __builtin_amdgcn_cvt_pk_f32_fp8(v.x, true);
    float2v p2 = __builtin_amdgcn_cvt_pk_f32_fp8(v.y, false);
    float2v p3 = __builtin_amdgcn_cvt_pk_f32_fp8(v.y, true);
    a[0] += p0[0]; a[1] += p0[1]; a[2] += p1[0]; a[3] += p1[1];
    a[4] += p2[0]; a[5] += p2[1]; a[6] += p3[0]; a[7] += p3[1];
}
__device__ __forceinline__ uint2 ldrow(const uchar* __restrict__ Hs, int r, size_t off) {
    return *(const uint2*)(Hs + (size_t)r * DIM + off);
}

// ---- init: T-zero ∥ degree-count (interleaved) + Wsw + Bsw tail + P zero --
// cnt pre-zeroed by hipMemsetAsync. grid = IPAIR + 388 + 64 + 12 + 8 = 2040
__global__ void k_init(const int* __restrict__ ecol, int* __restrict__ cnt,
                       const float* __restrict__ W1, ushort* __restrict__ Wsw,
                       float* __restrict__ T, ushort* __restrict__ Bsw,
                       float* __restrict__ P) {
    int b = blockIdx.x, t = threadIdx.x;
    int role, id;
    if (b < IPAIR)            { role = b & 1; id = b >> 1; }            // 0=Tzero 1=deg
    else if (b < IPAIR + 388) { role = 1; id = TZB + (b - IPAIR); }     // deg 784..1171
    else if (b < IPAIR + 388 + 64) { role = 2; id = b - (IPAIR + 388); }
    else if (b < IPAIR + 388 + 64 + 12) { role = 3; id = b - (IPAIR + 388 + 64); }
    else { role = 4; id = b - (IPAIR + 388 + 64 + 12); }

    if (role == 0) {
        // zero T: 64*NNP floats = 802816 float4 = 784 blocks * 256 thr * 4
        float4* w4 = (float4*)T;
        int base = id * 256 + t;
#pragma unroll
        for (int i = 0; i < 4; ++i)
            w4[base + i * 200704] = make_float4(0.f, 0.f, 0.f, 0.f);
    } else if (role == 1) {
        int e = (id * 256 + t) * 2;
        if (e < NE) {
            int2 c = *(const int2*)(ecol + e);
            atomicAdd(&cnt[c.x], 1);
            atomicAdd(&cnt[c.y], 1);
        }
    } else if (role == 2) {
        int tid = id * 256 + t;           // 16384 entries
        int j = tid & 7;
        int lane = (tid >> 3) & 63;
        int frag = tid >> 9;              // nt*4+kc
        int nt = frag >> 2, kc = frag & 3;
        int k = kc * 32 + (lane >> 4) * 8 + j;
        int n = nt * 16 + (lane & 15);
        Wsw[tid] = f2bf(W1[k * DIM + n]);
    } else if (role == 3) {
        // zero Bsw tail fragment blocks (t32 = 1562..1567): 3072 float4
        int idx = id * 256 + t;
        ((float4*)(Bsw + BSW_TAIL_START))[idx] = make_float4(0.f, 0.f, 0.f, 0.f);
    } else {
        // zero P: 8192 floats = 2048 float4 = 8 blocks * 256
        int idx = id * 256 + t;
        ((float4*)P)[idx] = make_float4(0.f, 0.f, 0.f, 0.f);
    }
}

// ---- merged: ELL placement (random atomics) ∥ MFMA GEMM (streaming) -------
// Independent: placement uses cnt2 (fresh zero counter); gemm reads final cnt.
// Interleaved block roles for co-residency: latency work hides under GEMM.
__global__ __launch_bounds__(256) void k_fillgemm(const int* __restrict__ erow,
                                                  const int* __restrict__ ecol,
                                                  int* __restrict__ cnt2,
                                                  ushort* __restrict__ ell,
                                                  const float* __restrict__ Ain,
                                                  const ushort* __restrict__ Wsw,
                                                  const int* __restrict__ cnt,
                                                  uchar* __restrict__ Hs) {
    const int b = blockIdx.x, t = threadIdx.x;
    int role, id;
    if (b < PAIR) { role = b & 1; id = b >> 1; }     // 0=fill 1=gemm
    else          { role = 0; id = GEMMB + (b - PAIR); }

    if (role == 0) {
        int e = (id * 256 + t) * 2;
        if (e < NE) {
            int2 r = *(const int2*)(erow + e);
            int2 c = *(const int2*)(ecol + e);
            int p0 = atomicAdd(&cnt2[c.x], 1);
            if (p0 < CAP) ell[(size_t)c.x * CAP + p0] = (ushort)r.x;
            int p1 = atomicAdd(&cnt2[c.y], 1);
            if (p1 < CAP) ell[(size_t)c.y * CAP + p1] = (ushort)r.y;
        }
        return;
    }

    // ---- MFMA GEMM: Hs[n,c] = fp8(dinv[n] * sum_k x[n,k] W1[k,c]) ----
    const int wave = t >> 6, lane = t & 63;
    const int m = lane & 15, quad = lane >> 4;
    const int row0 = id * 64 + wave * 16;

    short8 bfrag[8][4];
#pragma unroll
    for (int nt = 0; nt < 8; ++nt)
#pragma unroll
        for (int kc = 0; kc < 4; ++kc)
            bfrag[nt][kc] = *(const short8*)(Wsw + ((nt * 4 + kc) * 64 + lane) * 8);

    float4v acc[8];
#pragma unroll
    for (int nt = 0; nt < 8; ++nt) acc[nt] = (float4v){0.f, 0.f, 0.f, 0.f};

    const int row = row0 + m;
    const int rclamp = row < NN ? row : NN - 1;

#pragma unroll
    for (int kc = 0; kc < 4; ++kc) {
        const float* ap = Ain + (size_t)rclamp * DIM + kc * 32 + quad * 8;
        float4 v0 = *(const float4*)ap;
        float4 v1 = *(const float4*)(ap + 4);
        union { short8 v; ushort u[8]; } tmp;
        tmp.u[0] = f2bf(v0.x); tmp.u[1] = f2bf(v0.y);
        tmp.u[2] = f2bf(v0.z); tmp.u[3] = f2bf(v0.w);
        tmp.u[4] = f2bf(v1.x); tmp.u[5] = f2bf(v1.y);
        tmp.u[6] = f2bf(v1.z); tmp.u[7] = f2bf(v1.w);
        short8 a = tmp.v;
#pragma unroll
        for (int nt = 0; nt < 8; ++nt)
            acc[nt] = __builtin_amdgcn_mfma_f32_16x16x32_bf16(a, bfrag[nt][kc], acc[nt], 0, 0, 0);
    }

    // C/D: col = nt*16 + (lane&15), row = row0 + quad*4 + reg
#pragma unroll
    for (int reg = 0; reg < 4; ++reg) {
        int r = row0 + quad * 4 + reg;
        if (r < NN) {
            float d = rsqrtf(1.0f + (float)cnt[r]);
#pragma unroll
            for (int nt = 0; nt < 8; ++nt)
                Hs[(size_t)r * DIM + nt * 16 + m] = f2fp8(d * acc[nt][reg]);
        }
    }
}

// -------- ELL gather (fp8 in, double-buffered) + T-build + frag-transpose --
// A2row = d * relu(d*(Hs[c]+sum Hs[r])+b1)  (dinv folded in!)
// T[batch[c]][r] += d per edge (+ self). 16 lanes/node, 16 nodes/block.
__global__ __launch_bounds__(256) void k_gather_ell(const ushort* __restrict__ ell,
                                                    const int* __restrict__ deg,
                                                    const int* __restrict__ batch,
                                                    const float* __restrict__ bias,
                                                    const uchar* __restrict__ Hs,
                                                    float* __restrict__ T,
                                                    ushort* __restrict__ Bsw) {
    const int t = threadIdx.x, b = blockIdx.x;
    const int tn = t >> 4, lane = t & 15;
    const int node = b * 16 + tn;
    const ushort* rowp = ell + (size_t)node * CAP;
    const int dg = deg[node];
    const float d = rsqrtf(1.0f + (float)dg);
    const int end = min(dg, CAP);
    float* Trow = T + (size_t)batch[node] * NNP;
    const size_t off = (size_t)lane * 8;

    float a[8] = {0.f, 0.f, 0.f, 0.f, 0.f, 0.f, 0.f, 0.f};
    accfp8(a, ldrow(Hs, node, off));                             // self loop
    if (lane == 0) atomicAdd(&Trow[node], d);                    // self T term

    int e = 0;
    if (end >= 8) {
        // prologue: load batch 0
        uint4 iv = *(const uint4*)(rowp);
        uint2 v0 = ldrow(Hs, iv.x & 0xffff, off), v1 = ldrow(Hs, iv.x >> 16, off);
        uint2 v2 = ldrow(Hs, iv.y & 0xffff, off), v3 = ldrow(Hs, iv.y >> 16, off);
        uint2 v4 = ldrow(Hs, iv.z & 0xffff, off), v5 = ldrow(Hs, iv.z >> 16, off);
        uint2 v6 = ldrow(Hs, iv.w & 0xffff, off), v7 = ldrow(Hs, iv.w >> 16, off);
        while (e + 16 <= end) {
            // prefetch next batch while current is in registers
            uint4 ivn = *(const uint4*)(rowp + e + 8);
            uint2 n0 = ldrow(Hs, ivn.x & 0xffff, off), n1 = ldrow(Hs, ivn.x >> 16, off);
            uint2 n2 = ldrow(Hs, ivn.y & 0xffff, off), n3 = ldrow(Hs, ivn.y >> 16, off);
            uint2 n4 = ldrow(Hs, ivn.z & 0xffff, off), n5 = ldrow(Hs, ivn.z >> 16, off);
            uint2 n6 = ldrow(Hs, ivn.w & 0xffff, off), n7 = ldrow(Hs, ivn.w >> 16, off);
            if (lane < 8) atomicAdd(&Trow[rowp[e + lane]], d);
            accfp8(a, v0); accfp8(a, v1); accfp8(a, v2); accfp8(a, v3);
            accfp8(a, v4); accfp8(a, v5); accfp8(a, v6); accfp8(a, v7);
            v0 = n0; v1 = n1; v2 = n2; v3 = n3;
            v4 = n4; v5 = n5; v6 = n6; v7 = n7;
            e += 8;
        }
        if (lane < 8) atomicAdd(&Trow[rowp[e + lane]], d);
        accfp8(a, v0); accfp8(a, v1); accfp8(a, v2); accfp8(a, v3);
        accfp8(a, v4); accfp8(a, v5); accfp8(a, v6); accfp8(a, v7);
        e += 8;
    }
    for (; e + 4 <= end; e += 4) {
        uint2 lv = *(const uint2*)(rowp + e);
        int r0 = lv.x & 0xffff, r1 = lv.x >> 16;
        int r2 = lv.y & 0xffff, r3 = lv.y >> 16;
        if (lane < 4) atomicAdd(&Trow[rowp[e + lane]], d);
        uint2 w0 = ldrow(Hs, r0, off), w1 = ldrow(Hs, r1, off);
        uint2 w2 = ldrow(Hs, r2, off), w3 = ldrow(Hs, r3, off);
        accfp8(a, w0); accfp8(a, w1); accfp8(a, w2); accfp8(a, w3);
    }
    for (; e < end; ++e) {
        int r = rowp[e];
        if (lane == 0) atomicAdd(&Trow[r], d);
        accfp8(a, ldrow(Hs, r, off));
    }

    float4 b0 = *(const float4*)(bias + off);
    float4 b1 = *(const float4*)(bias + off + 4);
    a[0] = fmaxf(fmaf(a[0], d, b0.x), 0.f); a[1] = fmaxf(fmaf(a[1], d, b0.y), 0.f);
    a[2] = fmaxf(fmaf(a[2], d, b0.z), 0.f); a[3] = fmaxf(fmaf(a[3], d, b0.w), 0.f);
    a[4] = fmaxf(fmaf(a[4], d, b1.x), 0.f); a[5] = fmaxf(fmaf(a[5], d, b1.y), 0.f);
    a[6] = fmaxf(fmaf(a[6], d, b1.z), 0.f); a[7] = fmaxf(fmaf(a[7], d, b1.w), 0.f);

    // stage linear tile in LDS (dinv folded: store d * relu(...))
    __shared__ ushort Lb[16][128];
    union { short8 v; ushort u[8]; } st;
    st.u[0] = f2bf(d * a[0]); st.u[1] = f2bf(d * a[1]);
    st.u[2] = f2bf(d * a[2]); st.u[3] = f2bf(d * a[3]);
    st.u[4] = f2bf(d * a[4]); st.u[5] = f2bf(d * a[5]);
    st.u[6] = f2bf(d * a[6]); st.u[7] = f2bf(d * a[7]);
    *(short8*)(&Lb[tn][lane * 8]) = st.v;
    __syncthreads();

    // transpose-read and store one coalesced 16B fragment chunk per thread
    const int nt = t >> 5, idx = t & 31;
    const int a_rel = (idx >> 4) & 1, fb = (idx >> 3) & 1, f7 = idx & 7;
    const int feat = nt * 16 + fb * 8 + f7;
    const int nl = a_rel * 8;
    uint4 o;
    o.x = (unsigned)Lb[nl + 0][feat] | ((unsigned)Lb[nl + 1][feat] << 16);
    o.y = (unsigned)Lb[nl + 2][feat] | ((unsigned)Lb[nl + 3][feat] << 16);
    o.z = (unsigned)Lb[nl + 4][feat] | ((unsigned)Lb[nl + 5][feat] << 16);
    o.w = (unsigned)Lb[nl + 6][feat] | ((unsigned)Lb[nl + 7][feat] << 16);
    size_t base = (size_t)(b >> 1) * 4096 + (size_t)nt * 512
                + (size_t)((b & 1) * 2 + a_rel) * 128 + (size_t)fb * 64 + (size_t)f7 * 8;
    *(uint4*)(Bsw + base) = o;
}

// ---------------- pool GEMM: P += T[64 x NNP] @ Bsw[NNP x 128] -------------
// (dinv already folded into Bsw rows.) split-K, b128 fragment loads.
__global__ __launch_bounds__(256) void k_pool_gemm(const float* __restrict__ T,
                                                   const ushort* __restrict__ Bsw,
                                                   float* __restrict__ partial) {
    const int t = threadIdx.x;
    const int wave = t >> 6, lane = t & 63;
    const int m = lane & 15, quad = lane >> 4;
    const int g = wave * 16 + m;
    const int k0 = blockIdx.x * KCH;

    float4v acc[8];
#pragma unroll
    for (int nt = 0; nt < 8; ++nt) acc[nt] = (float4v){0.f, 0.f, 0.f, 0.f};

#pragma unroll
    for (int s = 0; s < KCH / 32; ++s) {
        const int kb = k0 + s * 32 + quad * 8;
        const float* ap = T + (size_t)g * NNP + kb;
        float4 a0 = *(const float4*)ap;
        float4 a1 = *(const float4*)(ap + 4);
        union { short8 v; ushort u[8]; } af;
        af.u[0] = f2bf(a0.x); af.u[1] = f2bf(a0.y);
        af.u[2] = f2bf(a0.z); af.u[3] = f2bf(a0.w);
        af.u[4] = f2bf(a1.x); af.u[5] = f2bf(a1.y);
        af.u[6] = f2bf(a1.z); af.u[7] = f2bf(a1.w);

        const int t32 = (k0 >> 5) + s;
        const ushort* bb = Bsw + (size_t)t32 * 4096 + (size_t)lane * 8;
#pragma unroll
        for (int nt = 0; nt < 8; ++nt) {
            short8 bv = *(const short8*)(bb + nt * 512);
            acc[nt] = __builtin_amdgcn_mfma_f32_16x16x32_bf16(af.v, bv, acc[nt], 0, 0, 0);
        }
    }

    float* dst = partial + (size_t)blockIdx.x * (NG * DIM);
#pragma unroll
    for (int reg = 0; reg < 4; ++reg) {
        int gg = wave * 16 + quad * 4 + reg;
#pragma unroll
        for (int nt = 0; nt < 8; ++nt)
            dst[gg * DIM + nt * 16 + m] = acc[nt][reg];
    }
}

// ------- parallel split-K reduce: P[elem] += sum of 49 partials ------------
// 65536 threads (256 blocks): 8 chunks x 8192 elems, coalesced, 8-way atomics.
__global__ __launch_bounds__(256) void k_red(const float* __restrict__ partial,
                                             float* __restrict__ P) {
    int tid = blockIdx.x * 256 + threadIdx.x;
    int elem = tid & 8191, h = tid >> 13;       // h = 0..7, 49 partials each
    const float* pp = partial + (size_t)h * 49 * (NG * DIM) + elem;
    float s = 0.f;
#pragma unroll
    for (int i = 0; i < 49; ++i) s += pp[(size_t)i * (NG * DIM)];
    atomicAdd(&P[elem], s);
}

// ------- pooled = (P@W2)/cnt + b2; logits = pooled @ Wlin + blin -----------
__global__ __launch_bounds__(128) void k_final(const float* __restrict__ P,
                                               const float* __restrict__ W2,
                                               const float* __restrict__ b2,
                                               const float* __restrict__ Wlin,
                                               const float* __restrict__ blin,
                                               const int* __restrict__ batch,
                                               float* __restrict__ out) {
    const int g = blockIdx.x;
    const int t = threadIdx.x;
    int start;
    { int a = 0, bb = NN; while (a < bb) { int mm = (a + bb) >> 1; if (batch[mm] < g) a = mm + 1; else bb = mm; } start = a; }
    int endp;
    { int a = 0, bb = NN; while (a < bb) { int mm = (a + bb) >> 1; if (batch[mm] < g + 1) a = mm + 1; else bb = mm; } endp = a; }
    const int cnt = endp - start;

    __shared__ float Pl[DIM];
    __shared__ float pooled[DIM];
    Pl[t] = P[g * DIM + t];
    __syncthreads();
    float acc = 0.f;
    for (int k = 0; k < DIM; ++k) acc += Pl[k] * W2[k * DIM + t];   // fp32 W2
    pooled[t] = (cnt > 0) ? (acc / (float)cnt + b2[t]) : 0.f;
    __syncthreads();
    if (t < NCLS) {
        float s2 = blin[t];
        for (int k = 0; k < DIM; ++k) s2 += pooled[k] * Wlin[k * NCLS + t];
        out[g * NCLS + t] = s2;
    }
}

extern "C" void kernel_launch(void* const* d_in, const int* in_sizes, int n_in,
                              void* d_out, int out_size, void* d_ws, size_t ws_size,
                              hipStream_t stream) {
    const float* x    = (const float*)d_in[0];
    const float* W1   = (const float*)d_in[1];
    const float* b1   = (const float*)d_in[2];
    const float* W2   = (const float*)d_in[3];
    const float* b2   = (const float*)d_in[4];
    const float* Wlin = (const float*)d_in[5];
    const float* blin = (const float*)d_in[6];
    const int* eidx   = (const int*)d_in[7];   // [2, E] flat: rows then cols
    const int* batch  = (const int*)d_in[8];
    float* out = (float*)d_out;

    char* ws = (char*)d_ws;
    int*    cnt   = (int*)(ws + 0);             // NN ints (degrees after init)
    int*    cnt2  = (int*)(ws + 200000);        // NN ints (ELL slot counter)
    ushort* Wsw   = (ushort*)(ws + 400000);     // 32768 B (W1 frags)
    ushort* ell   = (ushort*)(ws + 433472);     // NN*CAP ushort = 6.4 MB
    uchar*  Hs1   = (uchar*)(ws + 6833472);     // NN*DIM fp8 = 6.4 MB
    float*  T     = (float*)(ws + 13233472);    // 64*NNP fp32 = 12845056 B
    ushort* Bsw   = (ushort*)(ws + 26078528);   // NNP*DIM bf16 frag layout = 12.8 MB
    float*  partial=(float*)(ws + 38923584);    // KBLK*NG*DIM fp32 = 12.8 MB
    float*  P     = (float*)(ws + 51768640);    // 64*DIM fp32 = 32 KB

    const int* erow = eidx;
    const int* ecol = eidx + NE;

    // zero both counters in one memset; then init (Tzero ∥ degree-count + prep)
    hipMemsetAsync(ws, 0, 400000, stream);
    k_init<<<IPAIR + 388 + 64 + 12 + 8, 256, 0, stream>>>(ecol, cnt, W1, Wsw, T, Bsw, P);

    // ELL placement ∥ layer-1 MFMA GEMM (independent, co-resident)
    k_fillgemm<<<PAIR + (FILLB - GEMMB), 256, 0, stream>>>(erow, ecol, cnt2, ell,
                                                           x, Wsw, cnt, Hs1);

    // gather: A2 (scaled by dinv) into Bsw fragments; T built
    k_gather_ell<<<NN / 16, 256, 0, stream>>>(ell, cnt, batch, b1, Hs1, T, Bsw);

    // layer 2 + pool, fully commuted: P = T @ Bsw (split-K partials)
    k_pool_gemm<<<KBLK, 256, 0, stream>>>(T, Bsw, partial);
    k_red<<<256, 256, 0, stream>>>(partial, P);

    // P@W2 (fp32) + /cnt + b2 + Wlin head
    k_final<<<NG, 128, 0, stream>>>(P, W2, b2, Wlin, blin, batch, out);
}

// Round 4
// 201.154 us; speedup vs baseline: 1.0621x; 1.0621x over previous
//
#include <hip/hip_runtime.h>

#define NN 50000     // nodes
#define NE 600000    // directed edges (self loops handled separately)
#define NG 64        // graphs
#define DIM 128      // feature dim (D == H == 128)
#define NCLS 10
#define SB 196       // ceil(NN/256)
#define NNP 50176    // SB*256 = 224*224 (padded K for pool GEMM)
#define KBLK 392     // split-K blocks for pool GEMM (KCH = 128 = 4 MFMA K-steps)
#define KCH 128      // K-chunk per block (KBLK*KCH == NNP)
#define CAP 64       // ELL row capacity (multinomial max deg ~33; 64 is safe)
#define E2B ((NE / 2 + 255) / 256)   // edge blocks, 2 edges/thread
#define BSW_TAIL_START ((size_t)(NN >> 5) * 4096)   // ushort idx of t32=1562 block

typedef unsigned short ushort;
typedef unsigned char uchar;
typedef __attribute__((ext_vector_type(8))) short short8;   // 8 bf16 (4 VGPRs)
typedef __attribute__((ext_vector_type(4))) float float4v;  // 4 fp32 acc
typedef __attribute__((ext_vector_type(2))) float float2v;

__device__ __forceinline__ ushort f2bf(float f) {
    unsigned u = __float_as_uint(f);
    u += 0x7fff + ((u >> 16) & 1);          // RNE
    return (ushort)(u >> 16);
}
// fp8 e4m3 (OCP) encode via HW cvt (RNE, satfinite)
__device__ __forceinline__ uchar f2fp8(float f) {
    int p = __builtin_amdgcn_cvt_pk_fp8_f32(f, f, 0, false);
    return (uchar)(p & 0xff);
}
// decode 8 fp8 (uint2) -> accumulate into a[0..7]
__device__ __forceinline__ void accfp8(float* a, uint2 v) {
    float2v p0 = __builtin_amdgcn_cvt_pk_f32_fp8(v.x, false);
    float2v p1 = __builtin_amdgcn_cvt_pk_f32_fp8(v.x, true);
    float2v p2 = __builtin_amdgcn_cvt_pk_f32_fp8(v.y, false);
    float2v p3 = __builtin_amdgcn_cvt_pk_f32_fp8(v.y, true);
    a[0] += p0[0]; a[1] += p0[1]; a[2] += p1[0]; a[3] += p1[1];
    a[4] += p2[0]; a[5] += p2[1]; a[6] += p3[0]; a[7] += p3[1];
}
__device__ __forceinline__ uint2 ldrow(const uchar* __restrict__ Hs, int r, size_t off) {
    return *(const uint2*)(Hs + (size_t)r * DIM + off);
}

// ---- init: zero cnt + W1 frag prep + zero T + Bsw tail --------------------
// grid = SB (cnt) + 64 (Wsw) + 784 (T) + 12 (Bsw tail) = 1056
__global__ void k_init(int* __restrict__ cnt, const float* __restrict__ W1,
                       ushort* __restrict__ Wsw, float* __restrict__ T,
                       ushort* __restrict__ Bsw) {
    int b = blockIdx.x, t = threadIdx.x;
    if (b < SB) {
        int i = b * 256 + t;
        if (i < NN) cnt[i] = 0;
    } else if (b < SB + 64) {
        int tid = (b - SB) * 256 + t;     // 16384 entries
        int j = tid & 7;
        int lane = (tid >> 3) & 63;
        int frag = tid >> 9;              // nt*4+kc
        int nt = frag >> 2, kc = frag & 3;
        int k = kc * 32 + (lane >> 4) * 8 + j;
        int n = nt * 16 + (lane & 15);
        Wsw[tid] = f2bf(W1[k * DIM + n]);
    } else if (b < SB + 64 + 784) {
        // zero T: 64*NNP floats = 802816 float4 = 784 blocks * 256 thr * 4
        float4* w4 = (float4*)T;
        int base = (b - SB - 64) * 256 + t;
#pragma unroll
        for (int i = 0; i < 4; ++i)
            w4[base + i * 200704] = make_float4(0.f, 0.f, 0.f, 0.f);
    } else {
        // zero Bsw tail fragment blocks (t32 = 1562..1567) before gather fills
        // the valid-node slots interleaved inside them. 24576 ushorts = 3072 f4.
        int idx = (b - (SB + 64 + 784)) * 256 + t;
        ((float4*)(Bsw + BSW_TAIL_START))[idx] = make_float4(0.f, 0.f, 0.f, 0.f);
    }
}

// ------- single-pass ELL fill by dst (2 edges/thread); cnt ends as degree --
// ELL entries are ushort (node ids < 65536): halves gather-side index reads.
__global__ void k_fill(const int* __restrict__ row, const int* __restrict__ col,
                       int* __restrict__ cnt, ushort* __restrict__ ell) {
    int e = (blockIdx.x * blockDim.x + threadIdx.x) * 2;
    if (e < NE) {
        int2 r = *(const int2*)(row + e);
        int2 c = *(const int2*)(col + e);
        int p0 = atomicAdd(&cnt[c.x], 1);
        if (p0 < CAP) ell[(size_t)c.x * CAP + p0] = (ushort)r.x;
        int p1 = atomicAdd(&cnt[c.y], 1);
        if (p1 < CAP) ell[(size_t)c.y * CAP + p1] = (ushort)r.y;
    }
}

// ---------------- MFMA GEMM: Hs[n,c] = fp8(dinv[n] * sum_k x[n,k] W1[k,c]) -
__global__ __launch_bounds__(256) void k_gemm_mfma(const float* __restrict__ Ain,
                                                   const ushort* __restrict__ Wsw,
                                                   const int* __restrict__ cnt,
                                                   uchar* __restrict__ Hs) {
    const int t = threadIdx.x;
    const int wave = t >> 6, lane = t & 63;
    const int m = lane & 15, quad = lane >> 4;
    const int row0 = blockIdx.x * 64 + wave * 16;

    short8 bfrag[8][4];
#pragma unroll
    for (int nt = 0; nt < 8; ++nt)
#pragma unroll
        for (int kc = 0; kc < 4; ++kc)
            bfrag[nt][kc] = *(const short8*)(Wsw + ((nt * 4 + kc) * 64 + lane) * 8);

    float4v acc[8];
#pragma unroll
    for (int nt = 0; nt < 8; ++nt) acc[nt] = (float4v){0.f, 0.f, 0.f, 0.f};

    const int row = row0 + m;
    const int rclamp = row < NN ? row : NN - 1;

#pragma unroll
    for (int kc = 0; kc < 4; ++kc) {
        const float* ap = Ain + (size_t)rclamp * DIM + kc * 32 + quad * 8;
        float4 v0 = *(const float4*)ap;
        float4 v1 = *(const float4*)(ap + 4);
        union { short8 v; ushort u[8]; } tmp;
        tmp.u[0] = f2bf(v0.x); tmp.u[1] = f2bf(v0.y);
        tmp.u[2] = f2bf(v0.z); tmp.u[3] = f2bf(v0.w);
        tmp.u[4] = f2bf(v1.x); tmp.u[5] = f2bf(v1.y);
        tmp.u[6] = f2bf(v1.z); tmp.u[7] = f2bf(v1.w);
        short8 a = tmp.v;
#pragma unroll
        for (int nt = 0; nt < 8; ++nt)
            acc[nt] = __builtin_amdgcn_mfma_f32_16x16x32_bf16(a, bfrag[nt][kc], acc[nt], 0, 0, 0);
    }

    // C/D: col = nt*16 + (lane&15), row = row0 + quad*4 + reg
#pragma unroll
    for (int reg = 0; reg < 4; ++reg) {
        int r = row0 + quad * 4 + reg;
        if (r < NN) {
            float d = rsqrtf(1.0f + (float)cnt[r]);
#pragma unroll
            for (int nt = 0; nt < 8; ++nt)
                Hs[(size_t)r * DIM + nt * 16 + m] = f2fp8(d * acc[nt][reg]);
        }
    }
}

// -------- ELL gather (fp8 in) + fused T-build + LDS frag-transpose ---------
// Bsw row = bf16(d * relu(d*(Hs[c]+sum Hs[r])+b1))  (dinv folded in)
// T[batch[c]][r] += d per edge (+ self). 16 lanes/node, 16 nodes/block.
// Epilogue: block's 16x128 bf16 tile transposed through LDS into the
// MFMA-B-fragment layout of Bsw with fully coalesced uint4 stores:
//   E(node,feat) = (node>>5)*4096 + (feat>>4)*512 + ((node>>3)&3)*128
//                + ((feat>>3)&1)*64 + (feat&7)*8 + (node&7)
__global__ __launch_bounds__(256) void k_gather_ell(const ushort* __restrict__ ell,
                                                    const int* __restrict__ deg,
                                                    const int* __restrict__ batch,
                                                    const float* __restrict__ bias,
                                                    const uchar* __restrict__ Hs,
                                                    float* __restrict__ T,
                                                    ushort* __restrict__ Bsw) {
    const int t = threadIdx.x, b = blockIdx.x;
    const int tn = t >> 4, lane = t & 15;
    const int node = b * 16 + tn;
    const ushort* rowp = ell + (size_t)node * CAP;
    int end = min(deg[node], CAP);
    const float d = rsqrtf(1.0f + (float)deg[node]);
    float* Trow = T + (size_t)batch[node] * NNP;
    const size_t off = (size_t)lane * 8;

    float a[8] = {0.f, 0.f, 0.f, 0.f, 0.f, 0.f, 0.f, 0.f};
    accfp8(a, ldrow(Hs, node, off));                             // self loop
    if (lane == 0) atomicAdd(&Trow[node], d);                    // self T term

    int e = 0;
    for (; e + 8 <= end; e += 8) {
        uint4 iv = *(const uint4*)(rowp + e);
        int r0 = iv.x & 0xffff, r1 = iv.x >> 16;
        int r2 = iv.y & 0xffff, r3 = iv.y >> 16;
        int r4 = iv.z & 0xffff, r5 = iv.z >> 16;
        int r6 = iv.w & 0xffff, r7 = iv.w >> 16;
        if (lane < 8) atomicAdd(&Trow[rowp[e + lane]], d);
        uint2 v0 = ldrow(Hs, r0, off), v1 = ldrow(Hs, r1, off);
        uint2 v2 = ldrow(Hs, r2, off), v3 = ldrow(Hs, r3, off);
        uint2 v4 = ldrow(Hs, r4, off), v5 = ldrow(Hs, r5, off);
        uint2 v6 = ldrow(Hs, r6, off), v7 = ldrow(Hs, r7, off);
        accfp8(a, v0); accfp8(a, v1); accfp8(a, v2); accfp8(a, v3);
        accfp8(a, v4); accfp8(a, v5); accfp8(a, v6); accfp8(a, v7);
    }
    for (; e + 4 <= end; e += 4) {
        uint2 lv = *(const uint2*)(rowp + e);
        int r0 = lv.x & 0xffff, r1 = lv.x >> 16;
        int r2 = lv.y & 0xffff, r3 = lv.y >> 16;
        if (lane < 4) atomicAdd(&Trow[rowp[e + lane]], d);
        uint2 v0 = ldrow(Hs, r0, off), v1 = ldrow(Hs, r1, off);
        uint2 v2 = ldrow(Hs, r2, off), v3 = ldrow(Hs, r3, off);
        accfp8(a, v0); accfp8(a, v1); accfp8(a, v2); accfp8(a, v3);
    }
    for (; e < end; ++e) {
        int r = rowp[e];
        if (lane == 0) atomicAdd(&Trow[r], d);
        accfp8(a, ldrow(Hs, r, off));
    }

    float4 b0 = *(const float4*)(bias + off);
    float4 b1 = *(const float4*)(bias + off + 4);
    a[0] = fmaxf(fmaf(a[0], d, b0.x), 0.f); a[1] = fmaxf(fmaf(a[1], d, b0.y), 0.f);
    a[2] = fmaxf(fmaf(a[2], d, b0.z), 0.f); a[3] = fmaxf(fmaf(a[3], d, b0.w), 0.f);
    a[4] = fmaxf(fmaf(a[4], d, b1.x), 0.f); a[5] = fmaxf(fmaf(a[5], d, b1.y), 0.f);
    a[6] = fmaxf(fmaf(a[6], d, b1.z), 0.f); a[7] = fmaxf(fmaf(a[7], d, b1.w), 0.f);

    // stage linear tile in LDS (dinv folded: store d * relu(...))
    __shared__ ushort Lb[16][128];
    union { short8 v; ushort u[8]; } st;
    st.u[0] = f2bf(d * a[0]); st.u[1] = f2bf(d * a[1]);
    st.u[2] = f2bf(d * a[2]); st.u[3] = f2bf(d * a[3]);
    st.u[4] = f2bf(d * a[4]); st.u[5] = f2bf(d * a[5]);
    st.u[6] = f2bf(d * a[6]); st.u[7] = f2bf(d * a[7]);
    *(short8*)(&Lb[tn][lane * 8]) = st.v;
    __syncthreads();

    // transpose-read and store one coalesced 16B fragment chunk per thread
    const int nt = t >> 5, idx = t & 31;
    const int a_rel = (idx >> 4) & 1, fb = (idx >> 3) & 1, f7 = idx & 7;
    const int feat = nt * 16 + fb * 8 + f7;
    const int nl = a_rel * 8;
    uint4 o;
    o.x = (unsigned)Lb[nl + 0][feat] | ((unsigned)Lb[nl + 1][feat] << 16);
    o.y = (unsigned)Lb[nl + 2][feat] | ((unsigned)Lb[nl + 3][feat] << 16);
    o.z = (unsigned)Lb[nl + 4][feat] | ((unsigned)Lb[nl + 5][feat] << 16);
    o.w = (unsigned)Lb[nl + 6][feat] | ((unsigned)Lb[nl + 7][feat] << 16);
    size_t base = (size_t)(b >> 1) * 4096 + (size_t)nt * 512
                + (size_t)((b & 1) * 2 + a_rel) * 128 + (size_t)fb * 64 + (size_t)f7 * 8;
    *(uint4*)(Bsw + base) = o;
}

// ---------------- pool GEMM: P += T[64 x NNP] @ Bsw[NNP x 128] -------------
// (dinv folded into Bsw rows.) split-K, b128 fragment loads, no atomics.
__global__ __launch_bounds__(256) void k_pool_gemm(const float* __restrict__ T,
                                                   const ushort* __restrict__ Bsw,
                                                   float* __restrict__ partial) {
    const int t = threadIdx.x;
    const int wave = t >> 6, lane = t & 63;
    const int m = lane & 15, quad = lane >> 4;
    const int g = wave * 16 + m;
    const int k0 = blockIdx.x * KCH;

    float4v acc[8];
#pragma unroll
    for (int nt = 0; nt < 8; ++nt) acc[nt] = (float4v){0.f, 0.f, 0.f, 0.f};

#pragma unroll
    for (int s = 0; s < KCH / 32; ++s) {
        const int kb = k0 + s * 32 + quad * 8;
        const float* ap = T + (size_t)g * NNP + kb;
        float4 a0 = *(const float4*)ap;
        float4 a1 = *(const float4*)(ap + 4);
        union { short8 v; ushort u[8]; } af;
        af.u[0] = f2bf(a0.x); af.u[1] = f2bf(a0.y);
        af.u[2] = f2bf(a0.z); af.u[3] = f2bf(a0.w);
        af.u[4] = f2bf(a1.x); af.u[5] = f2bf(a1.y);
        af.u[6] = f2bf(a1.z); af.u[7] = f2bf(a1.w);

        const int t32 = (k0 >> 5) + s;
        const ushort* bb = Bsw + (size_t)t32 * 4096 + (size_t)lane * 8;
#pragma unroll
        for (int nt = 0; nt < 8; ++nt) {
            short8 bv = *(const short8*)(bb + nt * 512);
            acc[nt] = __builtin_amdgcn_mfma_f32_16x16x32_bf16(af.v, bv, acc[nt], 0, 0, 0);
        }
    }

    float* dst = partial + (size_t)blockIdx.x * (NG * DIM);
#pragma unroll
    for (int reg = 0; reg < 4; ++reg) {
        int gg = wave * 16 + quad * 4 + reg;
#pragma unroll
        for (int nt = 0; nt < 8; ++nt)
            dst[gg * DIM + nt * 16 + m] = acc[nt][reg];
    }
}

// ------- reduce partials; pooled = (P@W2)/cnt + b2; logits -----------------
// 512 threads: 4-way split of the 392-partial reduction per column.
__global__ __launch_bounds__(512) void k_final(const float* __restrict__ partial,
                                               const float* __restrict__ W2,
                                               const float* __restrict__ b2,
                                               const float* __restrict__ Wlin,
                                               const float* __restrict__ blin,
                                               const int* __restrict__ batch,
                                               float* __restrict__ out) {
    const int g = blockIdx.x;
    const int t = threadIdx.x;
    const int c = t & 127, h = t >> 7;          // h = 0..3, 98 partials each

    float s0 = 0.f, s1 = 0.f;
    const float* pp = partial + (size_t)h * 98 * (NG * DIM) + g * DIM + c;
#pragma unroll 7
    for (int i = 0; i < 98; i += 2) {
        s0 += pp[(size_t)i * (NG * DIM)];
        s1 += pp[(size_t)(i + 1) * (NG * DIM)];
    }

    __shared__ float red[512];
    __shared__ float Pl[DIM];
    __shared__ float pooled[DIM];
    red[t] = s0 + s1;
    __syncthreads();
    if (t < 128) Pl[t] = red[t] + red[t + 128] + red[t + 256] + red[t + 384];
    __syncthreads();
    if (t < 128) {
        float acc = 0.f;
        for (int k = 0; k < DIM; ++k) acc += Pl[k] * W2[k * DIM + t];   // fp32 W2
        int start;
        { int a = 0, bb = NN; while (a < bb) { int mm = (a + bb) >> 1; if (batch[mm] < g) a = mm + 1; else bb = mm; } start = a; }
        int endp;
        { int a = 0, bb = NN; while (a < bb) { int mm = (a + bb) >> 1; if (batch[mm] < g + 1) a = mm + 1; else bb = mm; } endp = a; }
        const int cnt = endp - start;
        pooled[t] = (cnt > 0) ? (acc / (float)cnt + b2[t]) : 0.f;
    }
    __syncthreads();
    if (t < NCLS) {
        float s2 = blin[t];
        for (int k = 0; k < DIM; ++k) s2 += pooled[k] * Wlin[k * NCLS + t];
        out[g * NCLS + t] = s2;
    }
}

extern "C" void kernel_launch(void* const* d_in, const int* in_sizes, int n_in,
                              void* d_out, int out_size, void* d_ws, size_t ws_size,
                              hipStream_t stream) {
    const float* x    = (const float*)d_in[0];
    const float* W1   = (const float*)d_in[1];
    const float* b1   = (const float*)d_in[2];
    const float* W2   = (const float*)d_in[3];
    const float* b2   = (const float*)d_in[4];
    const float* Wlin = (const float*)d_in[5];
    const float* blin = (const float*)d_in[6];
    const int* eidx   = (const int*)d_in[7];   // [2, E] flat: rows then cols
    const int* batch  = (const int*)d_in[8];
    float* out = (float*)d_out;

    char* ws = (char*)d_ws;
    int*    cnt   = (int*)(ws + 0);             // NN ints (zeroed; ends as degree)
    ushort* Wsw   = (ushort*)(ws + 400704);     // 32768 B (W1 frags)
    ushort* ell   = (ushort*)(ws + 433472);     // NN*CAP ushort = 6.4 MB
    uchar*  Hs1   = (uchar*)(ws + 6833472);     // NN*DIM fp8 = 6.4 MB
    float*  T     = (float*)(ws + 13233472);    // 64*NNP fp32 = 12845056 B
    ushort* Bsw   = (ushort*)(ws + 26078528);   // NNP*DIM bf16 frag layout = 12.8 MB
    float*  partial=(float*)(ws + 38923584);    // KBLK*NG*DIM fp32 = 12.8 MB

    const int* erow = eidx;
    const int* ecol = eidx + NE;

    // ---- structure build: zero+Wprep+Bsw-tail-zero, single-pass ELL fill ----
    k_init<<<SB + 64 + 784 + 12, 256, 0, stream>>>(cnt, W1, Wsw, T, Bsw);
    k_fill<<<E2B, 256, 0, stream>>>(erow, ecol, cnt, ell);

    const int gemm_grid = (NN + 63) / 64;            // 782
    const int node_grid = NN / 16;                   // 3125 (exact, 16 nodes/block)

    // layer 1: Hs1 = fp8(dinv*(x @ W1)); Bsw = frag(d*relu(dinv*agg+b1)); T built
    k_gemm_mfma<<<gemm_grid, 256, 0, stream>>>(x, Wsw, cnt, Hs1);
    k_gather_ell<<<node_grid, 256, 0, stream>>>(ell, cnt, batch, b1, Hs1, T, Bsw);

    // layer 2 + pool, fully commuted: P = T @ Bsw (split-K partials)
    k_pool_gemm<<<KBLK, 256, 0, stream>>>(T, Bsw, partial);

    // reduce + P@W2 (fp32) + /cnt + b2 + Wlin head
    k_final<<<NG, 512, 0, stream>>>(partial, W2, b2, Wlin, blin, batch, out);
}

// Round 5
// 193.240 us; speedup vs baseline: 1.1056x; 1.0410x over previous
//
#include <hip/hip_runtime.h>

#define NN 50000     // nodes
#define NE 600000    // directed edges (self loops handled separately)
#define NG 64        // graphs
#define DIM 128      // feature dim (D == H == 128)
#define NCLS 10
#define SB 196       // ceil(NN/256)
#define NNP 50176    // SB*256 = 224*224 (padded K for pool GEMM)
#define KBLK 392     // split-K blocks for pool GEMM (KCH = 128 = 4 MFMA K-steps)
#define KCH 128      // K-chunk per block (KBLK*KCH == NNP)
#define CAP 64       // ELL row capacity (multinomial max deg ~33; 64 is safe)
#define E4B ((NE / 4 + 255) / 256)   // edge blocks, 4 edges/thread = 586
#define BSW_TAIL_START ((size_t)(NN >> 5) * 4096)   // ushort idx of t32=1562 block

typedef unsigned short ushort;
typedef unsigned char uchar;
typedef __attribute__((ext_vector_type(8))) short short8;   // 8 bf16 (4 VGPRs)
typedef __attribute__((ext_vector_type(4))) float float4v;  // 4 fp32 acc
typedef __attribute__((ext_vector_type(2))) float float2v;

__device__ __forceinline__ ushort f2bf(float f) {
    unsigned u = __float_as_uint(f);
    u += 0x7fff + ((u >> 16) & 1);          // RNE
    return (ushort)(u >> 16);
}
// fp8 e4m3 (OCP) encode via HW cvt (RNE, satfinite)
__device__ __forceinline__ uchar f2fp8(float f) {
    int p = __builtin_amdgcn_cvt_pk_fp8_f32(f, f, 0, false);
    return (uchar)(p & 0xff);
}
// decode 8 fp8 (uint2) -> accumulate into a[0..7]
__device__ __forceinline__ void accfp8(float* a, uint2 v) {
    float2v p0 = __builtin_amdgcn_cvt_pk_f32_fp8(v.x, false);
    float2v p1 = __builtin_amdgcn_cvt_pk_f32_fp8(v.x, true);
    float2v p2 = __builtin_amdgcn_cvt_pk_f32_fp8(v.y, false);
    float2v p3 = __builtin_amdgcn_cvt_pk_f32_fp8(v.y, true);
    a[0] += p0[0]; a[1] += p0[1]; a[2] += p1[0]; a[3] += p1[1];
    a[4] += p2[0]; a[5] += p2[1]; a[6] += p3[0]; a[7] += p3[1];
}
__device__ __forceinline__ uint2 ldrow(const uchar* __restrict__ Hs, int r, size_t off) {
    return *(const uint2*)(Hs + (size_t)r * DIM + off);
}

// ---- init: zero cnt + W1 frag prep + zero T + Bsw tail + zero P -----------
// grid = SB (cnt) + 64 (Wsw) + 784 (T) + 12 (Bsw tail) + 1 (P) = 1057
__global__ void k_init(int* __restrict__ cnt, const float* __restrict__ W1,
                       ushort* __restrict__ Wsw, float* __restrict__ T,
                       ushort* __restrict__ Bsw, float* __restrict__ P) {
    int b = blockIdx.x, t = threadIdx.x;
    if (b < SB) {
        int i = b * 256 + t;
        if (i < NN) cnt[i] = 0;
    } else if (b < SB + 64) {
        int tid = (b - SB) * 256 + t;     // 16384 entries
        int j = tid & 7;
        int lane = (tid >> 3) & 63;
        int frag = tid >> 9;              // nt*4+kc
        int nt = frag >> 2, kc = frag & 3;
        int k = kc * 32 + (lane >> 4) * 8 + j;
        int n = nt * 16 + (lane & 15);
        Wsw[tid] = f2bf(W1[k * DIM + n]);
    } else if (b < SB + 64 + 784) {
        // zero T: 64*NNP floats = 802816 float4 = 784 blocks * 256 thr * 4
        float4* w4 = (float4*)T;
        int base = (b - SB - 64) * 256 + t;
#pragma unroll
        for (int i = 0; i < 4; ++i)
            w4[base + i * 200704] = make_float4(0.f, 0.f, 0.f, 0.f);
    } else if (b < SB + 64 + 784 + 12) {
        // zero Bsw tail fragment blocks (t32 = 1562..1567) before gather fills
        // the valid-node slots interleaved inside them. 24576 ushorts = 3072 f4.
        int idx = (b - (SB + 64 + 784)) * 256 + t;
        ((float4*)(Bsw + BSW_TAIL_START))[idx] = make_float4(0.f, 0.f, 0.f, 0.f);
    } else {
        // zero P: 8192 floats = 2048 float4 (one block, 8 per thread)
#pragma unroll
        for (int i = 0; i < 8; ++i)
            ((float4*)P)[i * 256 + t] = make_float4(0.f, 0.f, 0.f, 0.f);
    }
}

// ------- single-pass ELL fill by dst (4 edges/thread); cnt ends as degree --
// 4 independent atomic->store chains per thread for MLP; ushort entries.
__global__ void k_fill(const int* __restrict__ row, const int* __restrict__ col,
                       int* __restrict__ cnt, ushort* __restrict__ ell) {
    int e = (blockIdx.x * blockDim.x + threadIdx.x) * 4;
    if (e < NE) {   // NE % 4 == 0: full quads only
        int4 r = *(const int4*)(row + e);
        int4 c = *(const int4*)(col + e);
        int p0 = atomicAdd(&cnt[c.x], 1);
        int p1 = atomicAdd(&cnt[c.y], 1);
        int p2 = atomicAdd(&cnt[c.z], 1);
        int p3 = atomicAdd(&cnt[c.w], 1);
        if (p0 < CAP) ell[(size_t)c.x * CAP + p0] = (ushort)r.x;
        if (p1 < CAP) ell[(size_t)c.y * CAP + p1] = (ushort)r.y;
        if (p2 < CAP) ell[(size_t)c.z * CAP + p2] = (ushort)r.z;
        if (p3 < CAP) ell[(size_t)c.w * CAP + p3] = (ushort)r.w;
    }
}

// ---------------- MFMA GEMM: Hs[n,c] = fp8(dinv[n] * sum_k x[n,k] W1[k,c]) -
// v2: A preloaded (8 HBM loads in flight), B-frags loaded per-kc section
// (L2-hot 32KB Wsw); __launch_bounds__(256,4) caps VGPR at 128 so bfrag
// residency stays one kc deep -> 4 waves/SIMD instead of 2.
__global__ __launch_bounds__(256, 4) void k_gemm_mfma(const float* __restrict__ Ain,
                                                      const ushort* __restrict__ Wsw,
                                                      const int* __restrict__ cnt,
                                                      uchar* __restrict__ Hs) {
    const int t = threadIdx.x;
    const int wave = t >> 6, lane = t & 63;
    const int m = lane & 15, quad = lane >> 4;
    const int row0 = blockIdx.x * 64 + wave * 16;
    const int row = row0 + m;
    const int rclamp = row < NN ? row : NN - 1;

    // preload all 4 K-chunks of A (8 dwordx4 outstanding), convert to bf16
    float4 v[8];
    const float* ap = Ain + (size_t)rclamp * DIM + quad * 8;
#pragma unroll
    for (int kc = 0; kc < 4; ++kc) {
        v[2 * kc]     = *(const float4*)(ap + kc * 32);
        v[2 * kc + 1] = *(const float4*)(ap + kc * 32 + 4);
    }
    short8 afrag[4];
#pragma unroll
    for (int kc = 0; kc < 4; ++kc) {
        union { short8 s; ushort u[8]; } tmp;
        tmp.u[0] = f2bf(v[2 * kc].x);     tmp.u[1] = f2bf(v[2 * kc].y);
        tmp.u[2] = f2bf(v[2 * kc].z);     tmp.u[3] = f2bf(v[2 * kc].w);
        tmp.u[4] = f2bf(v[2 * kc + 1].x); tmp.u[5] = f2bf(v[2 * kc + 1].y);
        tmp.u[6] = f2bf(v[2 * kc + 1].z); tmp.u[7] = f2bf(v[2 * kc + 1].w);
        afrag[kc] = tmp.s;
    }

    float4v acc[8];
#pragma unroll
    for (int nt = 0; nt < 8; ++nt) acc[nt] = (float4v){0.f, 0.f, 0.f, 0.f};

    // per-kc sections: load 8 B-frags, then 8 MFMAs (static indices only)
#pragma unroll
    for (int kc = 0; kc < 4; ++kc) {
        const ushort* wp = Wsw + (size_t)kc * 512 + (size_t)lane * 8;
        short8 bfr[8];
#pragma unroll
        for (int nt = 0; nt < 8; ++nt)
            bfr[nt] = *(const short8*)(wp + (size_t)nt * 2048);
#pragma unroll
        for (int nt = 0; nt < 8; ++nt)
            acc[nt] = __builtin_amdgcn_mfma_f32_16x16x32_bf16(afrag[kc], bfr[nt], acc[nt], 0, 0, 0);
    }

    // C/D: col = nt*16 + (lane&15), row = row0 + quad*4 + reg
#pragma unroll
    for (int reg = 0; reg < 4; ++reg) {
        int r = row0 + quad * 4 + reg;
        if (r < NN) {
            float d = rsqrtf(1.0f + (float)cnt[r]);
#pragma unroll
            for (int nt = 0; nt < 8; ++nt)
                Hs[(size_t)r * DIM + nt * 16 + m] = f2fp8(d * acc[nt][reg]);
        }
    }
}

// -------- ELL gather (fp8 in) + fused T-build + LDS frag-transpose ---------
// Bsw row = bf16(d * relu(d*(Hs[c]+sum Hs[r])+b1))  (dinv folded in)
// T[batch[c]][r] += d per edge (+ self). 16 lanes/node, 16 nodes/block.
// (unchanged from round 2/4: 36 VGPR, ~56% occupancy is the measured optimum)
__global__ __launch_bounds__(256) void k_gather_ell(const ushort* __restrict__ ell,
                                                    const int* __restrict__ deg,
                                                    const int* __restrict__ batch,
                                                    const float* __restrict__ bias,
                                                    const uchar* __restrict__ Hs,
                                                    float* __restrict__ T,
                                                    ushort* __restrict__ Bsw) {
    const int t = threadIdx.x, b = blockIdx.x;
    const int tn = t >> 4, lane = t & 15;
    const int node = b * 16 + tn;
    const ushort* rowp = ell + (size_t)node * CAP;
    int end = min(deg[node], CAP);
    const float d = rsqrtf(1.0f + (float)deg[node]);
    float* Trow = T + (size_t)batch[node] * NNP;
    const size_t off = (size_t)lane * 8;

    float a[8] = {0.f, 0.f, 0.f, 0.f, 0.f, 0.f, 0.f, 0.f};
    accfp8(a, ldrow(Hs, node, off));                             // self loop
    if (lane == 0) atomicAdd(&Trow[node], d);                    // self T term

    int e = 0;
    for (; e + 8 <= end; e += 8) {
        uint4 iv = *(const uint4*)(rowp + e);
        int r0 = iv.x & 0xffff, r1 = iv.x >> 16;
        int r2 = iv.y & 0xffff, r3 = iv.y >> 16;
        int r4 = iv.z & 0xffff, r5 = iv.z >> 16;
        int r6 = iv.w & 0xffff, r7 = iv.w >> 16;
        if (lane < 8) atomicAdd(&Trow[rowp[e + lane]], d);
        uint2 v0 = ldrow(Hs, r0, off), v1 = ldrow(Hs, r1, off);
        uint2 v2 = ldrow(Hs, r2, off), v3 = ldrow(Hs, r3, off);
        uint2 v4 = ldrow(Hs, r4, off), v5 = ldrow(Hs, r5, off);
        uint2 v6 = ldrow(Hs, r6, off), v7 = ldrow(Hs, r7, off);
        accfp8(a, v0); accfp8(a, v1); accfp8(a, v2); accfp8(a, v3);
        accfp8(a, v4); accfp8(a, v5); accfp8(a, v6); accfp8(a, v7);
    }
    for (; e + 4 <= end; e += 4) {
        uint2 lv = *(const uint2*)(rowp + e);
        int r0 = lv.x & 0xffff, r1 = lv.x >> 16;
        int r2 = lv.y & 0xffff, r3 = lv.y >> 16;
        if (lane < 4) atomicAdd(&Trow[rowp[e + lane]], d);
        uint2 v0 = ldrow(Hs, r0, off), v1 = ldrow(Hs, r1, off);
        uint2 v2 = ldrow(Hs, r2, off), v3 = ldrow(Hs, r3, off);
        accfp8(a, v0); accfp8(a, v1); accfp8(a, v2); accfp8(a, v3);
    }
    for (; e < end; ++e) {
        int r = rowp[e];
        if (lane == 0) atomicAdd(&Trow[r], d);
        accfp8(a, ldrow(Hs, r, off));
    }

    float4 b0 = *(const float4*)(bias + off);
    float4 b1 = *(const float4*)(bias + off + 4);
    a[0] = fmaxf(fmaf(a[0], d, b0.x), 0.f); a[1] = fmaxf(fmaf(a[1], d, b0.y), 0.f);
    a[2] = fmaxf(fmaf(a[2], d, b0.z), 0.f); a[3] = fmaxf(fmaf(a[3], d, b0.w), 0.f);
    a[4] = fmaxf(fmaf(a[4], d, b1.x), 0.f); a[5] = fmaxf(fmaf(a[5], d, b1.y), 0.f);
    a[6] = fmaxf(fmaf(a[6], d, b1.z), 0.f); a[7] = fmaxf(fmaf(a[7], d, b1.w), 0.f);

    // stage linear tile in LDS (dinv folded: store d * relu(...))
    __shared__ ushort Lb[16][128];
    union { short8 v; ushort u[8]; } st;
    st.u[0] = f2bf(d * a[0]); st.u[1] = f2bf(d * a[1]);
    st.u[2] = f2bf(d * a[2]); st.u[3] = f2bf(d * a[3]);
    st.u[4] = f2bf(d * a[4]); st.u[5] = f2bf(d * a[5]);
    st.u[6] = f2bf(d * a[6]); st.u[7] = f2bf(d * a[7]);
    *(short8*)(&Lb[tn][lane * 8]) = st.v;
    __syncthreads();

    // transpose-read and store one coalesced 16B fragment chunk per thread
    const int nt = t >> 5, idx = t & 31;
    const int a_rel = (idx >> 4) & 1, fb = (idx >> 3) & 1, f7 = idx & 7;
    const int feat = nt * 16 + fb * 8 + f7;
    const int nl = a_rel * 8;
    uint4 o;
    o.x = (unsigned)Lb[nl + 0][feat] | ((unsigned)Lb[nl + 1][feat] << 16);
    o.y = (unsigned)Lb[nl + 2][feat] | ((unsigned)Lb[nl + 3][feat] << 16);
    o.z = (unsigned)Lb[nl + 4][feat] | ((unsigned)Lb[nl + 5][feat] << 16);
    o.w = (unsigned)Lb[nl + 6][feat] | ((unsigned)Lb[nl + 7][feat] << 16);
    size_t base = (size_t)(b >> 1) * 4096 + (size_t)nt * 512
                + (size_t)((b & 1) * 2 + a_rel) * 128 + (size_t)fb * 64 + (size_t)f7 * 8;
    *(uint4*)(Bsw + base) = o;
}

// ---------------- pool GEMM: P += T[64 x NNP] @ Bsw[NNP x 128] -------------
// (dinv folded into Bsw rows.) split-K, b128 fragment loads, no atomics.
__global__ __launch_bounds__(256) void k_pool_gemm(const float* __restrict__ T,
                                                   const ushort* __restrict__ Bsw,
                                                   float* __restrict__ partial) {
    const int t = threadIdx.x;
    const int wave = t >> 6, lane = t & 63;
    const int m = lane & 15, quad = lane >> 4;
    const int g = wave * 16 + m;
    const int k0 = blockIdx.x * KCH;

    float4v acc[8];
#pragma unroll
    for (int nt = 0; nt < 8; ++nt) acc[nt] = (float4v){0.f, 0.f, 0.f, 0.f};

#pragma unroll
    for (int s = 0; s < KCH / 32; ++s) {
        const int kb = k0 + s * 32 + quad * 8;
        const float* ap = T + (size_t)g * NNP + kb;
        float4 a0 = *(const float4*)ap;
        float4 a1 = *(const float4*)(ap + 4);
        union { short8 v; ushort u[8]; } af;
        af.u[0] = f2bf(a0.x); af.u[1] = f2bf(a0.y);
        af.u[2] = f2bf(a0.z); af.u[3] = f2bf(a0.w);
        af.u[4] = f2bf(a1.x); af.u[5] = f2bf(a1.y);
        af.u[6] = f2bf(a1.z); af.u[7] = f2bf(a1.w);

        const int t32 = (k0 >> 5) + s;
        const ushort* bb = Bsw + (size_t)t32 * 4096 + (size_t)lane * 8;
#pragma unroll
        for (int nt = 0; nt < 8; ++nt) {
            short8 bv = *(const short8*)(bb + nt * 512);
            acc[nt] = __builtin_amdgcn_mfma_f32_16x16x32_bf16(af.v, bv, acc[nt], 0, 0, 0);
        }
    }

    float* dst = partial + (size_t)blockIdx.x * (NG * DIM);
#pragma unroll
    for (int reg = 0; reg < 4; ++reg) {
        int gg = wave * 16 + quad * 4 + reg;
#pragma unroll
        for (int nt = 0; nt < 8; ++nt)
            dst[gg * DIM + nt * 16 + m] = acc[nt][reg];
    }
}

// ------- parallel split-K reduce: P[elem] += sum of 49 partials ------------
// 65536 threads (256 blocks): 8 chunks x 8192 elems, coalesced, 8-way atomics.
__global__ __launch_bounds__(256) void k_red(const float* __restrict__ partial,
                                             float* __restrict__ P) {
    int tid = blockIdx.x * 256 + threadIdx.x;
    int elem = tid & 8191, h = tid >> 13;       // h = 0..7, 49 partials each
    const float* pp = partial + (size_t)h * 49 * (NG * DIM) + elem;
    float s = 0.f;
#pragma unroll
    for (int i = 0; i < 49; ++i) s += pp[(size_t)i * (NG * DIM)];
    atomicAdd(&P[elem], s);
}

// ------- pooled = (P@W2)/cnt + b2; logits = pooled @ Wlin + blin -----------
__global__ __launch_bounds__(128) void k_final(const float* __restrict__ P,
                                               const float* __restrict__ W2,
                                               const float* __restrict__ b2,
                                               const float* __restrict__ Wlin,
                                               const float* __restrict__ blin,
                                               const int* __restrict__ batch,
                                               float* __restrict__ out) {
    const int g = blockIdx.x;
    const int t = threadIdx.x;
    int start;
    { int a = 0, bb = NN; while (a < bb) { int mm = (a + bb) >> 1; if (batch[mm] < g) a = mm + 1; else bb = mm; } start = a; }
    int endp;
    { int a = 0, bb = NN; while (a < bb) { int mm = (a + bb) >> 1; if (batch[mm] < g + 1) a = mm + 1; else bb = mm; } endp = a; }
    const int cnt = endp - start;

    __shared__ float Pl[DIM];
    __shared__ float pooled[DIM];
    Pl[t] = P[g * DIM + t];
    __syncthreads();
    float acc = 0.f;
    for (int k = 0; k < DIM; ++k) acc += Pl[k] * W2[k * DIM + t];   // fp32 W2
    pooled[t] = (cnt > 0) ? (acc / (float)cnt + b2[t]) : 0.f;
    __syncthreads();
    if (t < NCLS) {
        float s2 = blin[t];
        for (int k = 0; k < DIM; ++k) s2 += pooled[k] * Wlin[k * NCLS + t];
        out[g * NCLS + t] = s2;
    }
}

extern "C" void kernel_launch(void* const* d_in, const int* in_sizes, int n_in,
                              void* d_out, int out_size, void* d_ws, size_t ws_size,
                              hipStream_t stream) {
    const float* x    = (const float*)d_in[0];
    const float* W1   = (const float*)d_in[1];
    const float* b1   = (const float*)d_in[2];
    const float* W2   = (const float*)d_in[3];
    const float* b2   = (const float*)d_in[4];
    const float* Wlin = (const float*)d_in[5];
    const float* blin = (const float*)d_in[6];
    const int* eidx   = (const int*)d_in[7];   // [2, E] flat: rows then cols
    const int* batch  = (const int*)d_in[8];
    float* out = (float*)d_out;

    char* ws = (char*)d_ws;
    int*    cnt   = (int*)(ws + 0);             // NN ints (zeroed; ends as degree)
    ushort* Wsw   = (ushort*)(ws + 400704);     // 32768 B (W1 frags)
    ushort* ell   = (ushort*)(ws + 433472);     // NN*CAP ushort = 6.4 MB
    uchar*  Hs1   = (uchar*)(ws + 6833472);     // NN*DIM fp8 = 6.4 MB
    float*  T     = (float*)(ws + 13233472);    // 64*NNP fp32 = 12845056 B
    ushort* Bsw   = (ushort*)(ws + 26078528);   // NNP*DIM bf16 frag layout = 12.8 MB
    float*  partial=(float*)(ws + 38923584);    // KBLK*NG*DIM fp32 = 12.8 MB
    float*  P     = (float*)(ws + 51768640);    // 64*DIM fp32 = 32 KB

    const int* erow = eidx;
    const int* ecol = eidx + NE;

    // ---- structure build: zero+Wprep+Bsw-tail+P-zero, single-pass ELL fill ----
    k_init<<<SB + 64 + 784 + 12 + 1, 256, 0, stream>>>(cnt, W1, Wsw, T, Bsw, P);
    k_fill<<<E4B, 256, 0, stream>>>(erow, ecol, cnt, ell);

    const int gemm_grid = (NN + 63) / 64;            // 782
    const int node_grid = NN / 16;                   // 3125 (exact, 16 nodes/block)

    // layer 1: Hs1 = fp8(dinv*(x @ W1)); Bsw = frag(d*relu(dinv*agg+b1)); T built
    k_gemm_mfma<<<gemm_grid, 256, 0, stream>>>(x, Wsw, cnt, Hs1);
    k_gather_ell<<<node_grid, 256, 0, stream>>>(ell, cnt, batch, b1, Hs1, T, Bsw);

    // layer 2 + pool, fully commuted: P = T @ Bsw (split-K partials + reduce)
    k_pool_gemm<<<KBLK, 256, 0, stream>>>(T, Bsw, partial);
    k_red<<<256, 256, 0, stream>>>(partial, P);

    // P@W2 (fp32) + /cnt + b2 + Wlin head
    k_final<<<NG, 128, 0, stream>>>(P, W2, b2, Wlin, blin, batch, out);
}

// Round 6
// 192.062 us; speedup vs baseline: 1.1123x; 1.0061x over previous
//
#include <hip/hip_runtime.h>

#define NN 50000     // nodes
#define NE 600000    // directed edges (self loops handled separately)
#define NG 64        // graphs
#define DIM 128      // feature dim (D == H == 128)
#define NCLS 10
#define SB 196       // ceil(NN/256)
#define NNP 50176    // SB*256 = 224*224 (padded K for pool GEMM)
#define KBLK 392     // split-K blocks for pool GEMM (KCH = 128 = 4 MFMA K-steps)
#define KCH 128      // K-chunk per block (KBLK*KCH == NNP)
#define CAP 64       // ELL row capacity (multinomial max deg ~33; 64 is safe)
#define E4B ((NE / 4 + 255) / 256)   // edge blocks, 4 edges/thread = 586
#define DUMMY 50000  // dummy node id (0xC350); Hs row DUMMY is zeroed
#define ELLQ (NN * CAP / 8)          // 400000 uint4 in ELL
#define ELLFB 391    // ELL prefill blocks (391*256*4 >= 400000)
#define BSW_TAIL_START ((size_t)(NN >> 5) * 4096)   // ushort idx of t32=1562 block

typedef unsigned short ushort;
typedef unsigned char uchar;
typedef __attribute__((ext_vector_type(8))) short short8;   // 8 bf16 (4 VGPRs)
typedef __attribute__((ext_vector_type(4))) float float4v;  // 4 fp32 acc
typedef __attribute__((ext_vector_type(2))) float float2v;

__device__ __forceinline__ ushort f2bf(float f) {
    unsigned u = __float_as_uint(f);
    u += 0x7fff + ((u >> 16) & 1);          // RNE
    return (ushort)(u >> 16);
}
// fp8 e4m3 (OCP) encode via HW cvt (RNE, satfinite)
__device__ __forceinline__ uchar f2fp8(float f) {
    int p = __builtin_amdgcn_cvt_pk_fp8_f32(f, f, 0, false);
    return (uchar)(p & 0xff);
}
// decode 8 fp8 (uint2) -> accumulate into a[0..7]
__device__ __forceinline__ void accfp8(float* a, uint2 v) {
    float2v p0 = __builtin_amdgcn_cvt_pk_f32_fp8(v.x, false);
    float2v p1 = __builtin_amdgcn_cvt_pk_f32_fp8(v.x, true);
    float2v p2 = __builtin_amdgcn_cvt_pk_f32_fp8(v.y, false);
    float2v p3 = __builtin_amdgcn_cvt_pk_f32_fp8(v.y, true);
    a[0] += p0[0]; a[1] += p0[1]; a[2] += p1[0]; a[3] += p1[1];
    a[4] += p2[0]; a[5] += p2[1]; a[6] += p3[0]; a[7] += p3[1];
}
__device__ __forceinline__ uint2 ldrow(const uchar* __restrict__ Hs, int r, size_t off) {
    return *(const uint2*)(Hs + (size_t)r * DIM + off);
}

// ---- init: cnt + Wsw + T-zero + Bsw tail + (P zero & Hs dummy row) + ELL --
// grid = 196 + 64 + 784 + 12 + 1 + 391 = 1448
__global__ void k_init(int* __restrict__ cnt, const float* __restrict__ W1,
                       ushort* __restrict__ Wsw, float* __restrict__ T,
                       ushort* __restrict__ Bsw, float* __restrict__ P,
                       uchar* __restrict__ Hs, ushort* __restrict__ ell) {
    int b = blockIdx.x, t = threadIdx.x;
    if (b < SB) {
        int i = b * 256 + t;
        if (i < NN) cnt[i] = 0;
    } else if (b < SB + 64) {
        int tid = (b - SB) * 256 + t;     // 16384 entries
        int j = tid & 7;
        int lane = (tid >> 3) & 63;
        int frag = tid >> 9;              // nt*4+kc
        int nt = frag >> 2, kc = frag & 3;
        int k = kc * 32 + (lane >> 4) * 8 + j;
        int n = nt * 16 + (lane & 15);
        Wsw[tid] = f2bf(W1[k * DIM + n]);
    } else if (b < SB + 64 + 784) {
        // zero T: 64*NNP floats = 802816 float4 = 784 blocks * 256 thr * 4
        float4* w4 = (float4*)T;
        int base = (b - SB - 64) * 256 + t;
#pragma unroll
        for (int i = 0; i < 4; ++i)
            w4[base + i * 200704] = make_float4(0.f, 0.f, 0.f, 0.f);
    } else if (b < SB + 64 + 784 + 12) {
        // zero Bsw tail fragment blocks (t32 = 1562..1567) before gather fills
        // the valid-node slots interleaved inside them. 24576 ushorts = 3072 f4.
        int idx = (b - (SB + 64 + 784)) * 256 + t;
        ((float4*)(Bsw + BSW_TAIL_START))[idx] = make_float4(0.f, 0.f, 0.f, 0.f);
    } else if (b == SB + 64 + 784 + 12) {
        // zero P: 8192 floats = 2048 float4 (one block, 8 per thread)
#pragma unroll
        for (int i = 0; i < 8; ++i)
            ((float4*)P)[i * 256 + t] = make_float4(0.f, 0.f, 0.f, 0.f);
        // zero the Hs dummy row (node DUMMY): 128 B = 8 x uint4
        if (t < 8)
            ((uint4*)(Hs + (size_t)DUMMY * DIM))[t] = make_uint4(0u, 0u, 0u, 0u);
    } else {
        // prefill ELL with DUMMY id (0xC350 pattern) so gather can run
        // uniform 8-wide batches; k_fill overwrites the first deg slots.
        int base = (b - (SB + 64 + 784 + 13)) * 256 + t;
        uint4 dv = make_uint4(0xC350C350u, 0xC350C350u, 0xC350C350u, 0xC350C350u);
#pragma unroll
        for (int i = 0; i < 4; ++i) {
            int idx = base + i * (ELLFB * 256);
            if (idx < ELLQ) ((uint4*)ell)[idx] = dv;
        }
    }
}

// ------- single-pass ELL fill by dst (4 edges/thread); cnt ends as degree --
// 4 independent atomic->store chains per thread for MLP; ushort entries.
__global__ void k_fill(const int* __restrict__ row, const int* __restrict__ col,
                       int* __restrict__ cnt, ushort* __restrict__ ell) {
    int e = (blockIdx.x * blockDim.x + threadIdx.x) * 4;
    if (e < NE) {   // NE % 4 == 0: full quads only
        int4 r = *(const int4*)(row + e);
        int4 c = *(const int4*)(col + e);
        int p0 = atomicAdd(&cnt[c.x], 1);
        int p1 = atomicAdd(&cnt[c.y], 1);
        int p2 = atomicAdd(&cnt[c.z], 1);
        int p3 = atomicAdd(&cnt[c.w], 1);
        if (p0 < CAP) ell[(size_t)c.x * CAP + p0] = (ushort)r.x;
        if (p1 < CAP) ell[(size_t)c.y * CAP + p1] = (ushort)r.y;
        if (p2 < CAP) ell[(size_t)c.z * CAP + p2] = (ushort)r.z;
        if (p3 < CAP) ell[(size_t)c.w * CAP + p3] = (ushort)r.w;
    }
}

// ---------------- MFMA GEMM: Hs[n,c] = fp8(dinv[n] * sum_k x[n,k] W1[k,c]) -
// A preloaded (8 HBM loads in flight), B-frags loaded per-kc section
// (L2-hot 32KB Wsw); __launch_bounds__(256,4) caps VGPR at 128.
__global__ __launch_bounds__(256, 4) void k_gemm_mfma(const float* __restrict__ Ain,
                                                      const ushort* __restrict__ Wsw,
                                                      const int* __restrict__ cnt,
                                                      uchar* __restrict__ Hs) {
    const int t = threadIdx.x;
    const int wave = t >> 6, lane = t & 63;
    const int m = lane & 15, quad = lane >> 4;
    const int row0 = blockIdx.x * 64 + wave * 16;
    const int row = row0 + m;
    const int rclamp = row < NN ? row : NN - 1;

    // preload all 4 K-chunks of A (8 dwordx4 outstanding), convert to bf16
    float4 v[8];
    const float* ap = Ain + (size_t)rclamp * DIM + quad * 8;
#pragma unroll
    for (int kc = 0; kc < 4; ++kc) {
        v[2 * kc]     = *(const float4*)(ap + kc * 32);
        v[2 * kc + 1] = *(const float4*)(ap + kc * 32 + 4);
    }
    short8 afrag[4];
#pragma unroll
    for (int kc = 0; kc < 4; ++kc) {
        union { short8 s; ushort u[8]; } tmp;
        tmp.u[0] = f2bf(v[2 * kc].x);     tmp.u[1] = f2bf(v[2 * kc].y);
        tmp.u[2] = f2bf(v[2 * kc].z);     tmp.u[3] = f2bf(v[2 * kc].w);
        tmp.u[4] = f2bf(v[2 * kc + 1].x); tmp.u[5] = f2bf(v[2 * kc + 1].y);
        tmp.u[6] = f2bf(v[2 * kc + 1].z); tmp.u[7] = f2bf(v[2 * kc + 1].w);
        afrag[kc] = tmp.s;
    }

    float4v acc[8];
#pragma unroll
    for (int nt = 0; nt < 8; ++nt) acc[nt] = (float4v){0.f, 0.f, 0.f, 0.f};

    // per-kc sections: load 8 B-frags, then 8 MFMAs (static indices only)
#pragma unroll
    for (int kc = 0; kc < 4; ++kc) {
        const ushort* wp = Wsw + (size_t)kc * 512 + (size_t)lane * 8;
        short8 bfr[8];
#pragma unroll
        for (int nt = 0; nt < 8; ++nt)
            bfr[nt] = *(const short8*)(wp + (size_t)nt * 2048);
#pragma unroll
        for (int nt = 0; nt < 8; ++nt)
            acc[nt] = __builtin_amdgcn_mfma_f32_16x16x32_bf16(afrag[kc], bfr[nt], acc[nt], 0, 0, 0);
    }

    // C/D: col = nt*16 + (lane&15), row = row0 + quad*4 + reg
#pragma unroll
    for (int reg = 0; reg < 4; ++reg) {
        int r = row0 + quad * 4 + reg;
        if (r < NN) {
            float d = rsqrtf(1.0f + (float)cnt[r]);
#pragma unroll
            for (int nt = 0; nt < 8; ++nt)
                Hs[(size_t)r * DIM + nt * 16 + m] = f2fp8(d * acc[nt][reg]);
        }
    }
}

// -------- ELL gather (fp8 in) + fused T-build + LDS frag-transpose ---------
// Bsw row = bf16(d * relu(d*(Hs[c]+sum Hs[r])+b1))  (dinv folded in)
// T[batch[c]][r] += d per edge (+ self). 16 lanes/node, 16 nodes/block.
// ELL rows are DUMMY-padded to 8: every batch is a uniform 8-wide gather
// (dummy slots read the zeroed Hs[DUMMY] row = exact 0 contribution);
// T-atomics stay guarded by e+lane < end so atomic count is unchanged.
__global__ __launch_bounds__(256) void k_gather_ell(const ushort* __restrict__ ell,
                                                    const int* __restrict__ deg,
                                                    const int* __restrict__ batch,
                                                    const float* __restrict__ bias,
                                                    const uchar* __restrict__ Hs,
                                                    float* __restrict__ T,
                                                    ushort* __restrict__ Bsw) {
    const int t = threadIdx.x, b = blockIdx.x;
    const int tn = t >> 4, lane = t & 15;
    const int node = b * 16 + tn;
    const ushort* rowp = ell + (size_t)node * CAP;
    int end = min(deg[node], CAP);
    const float d = rsqrtf(1.0f + (float)deg[node]);
    float* Trow = T + (size_t)batch[node] * NNP;
    const size_t off = (size_t)lane * 8;

    float a[8] = {0.f, 0.f, 0.f, 0.f, 0.f, 0.f, 0.f, 0.f};
    accfp8(a, ldrow(Hs, node, off));                             // self loop
    if (lane == 0) atomicAdd(&Trow[node], d);                    // self T term

    for (int e = 0; e < end; e += 8) {
        uint4 iv = *(const uint4*)(rowp + e);
        int r0 = iv.x & 0xffff, r1 = iv.x >> 16;
        int r2 = iv.y & 0xffff, r3 = iv.y >> 16;
        int r4 = iv.z & 0xffff, r5 = iv.z >> 16;
        int r6 = iv.w & 0xffff, r7 = iv.w >> 16;
        if (lane < 8 && e + lane < end) atomicAdd(&Trow[rowp[e + lane]], d);
        uint2 v0 = ldrow(Hs, r0, off), v1 = ldrow(Hs, r1, off);
        uint2 v2 = ldrow(Hs, r2, off), v3 = ldrow(Hs, r3, off);
        uint2 v4 = ldrow(Hs, r4, off), v5 = ldrow(Hs, r5, off);
        uint2 v6 = ldrow(Hs, r6, off), v7 = ldrow(Hs, r7, off);
        accfp8(a, v0); accfp8(a, v1); accfp8(a, v2); accfp8(a, v3);
        accfp8(a, v4); accfp8(a, v5); accfp8(a, v6); accfp8(a, v7);
    }

    float4 b0 = *(const float4*)(bias + off);
    float4 b1 = *(const float4*)(bias + off + 4);
    a[0] = fmaxf(fmaf(a[0], d, b0.x), 0.f); a[1] = fmaxf(fmaf(a[1], d, b0.y), 0.f);
    a[2] = fmaxf(fmaf(a[2], d, b0.z), 0.f); a[3] = fmaxf(fmaf(a[3], d, b0.w), 0.f);
    a[4] = fmaxf(fmaf(a[4], d, b1.x), 0.f); a[5] = fmaxf(fmaf(a[5], d, b1.y), 0.f);
    a[6] = fmaxf(fmaf(a[6], d, b1.z), 0.f); a[7] = fmaxf(fmaf(a[7], d, b1.w), 0.f);

    // stage linear tile in LDS (dinv folded: store d * relu(...))
    __shared__ ushort Lb[16][128];
    union { short8 v; ushort u[8]; } st;
    st.u[0] = f2bf(d * a[0]); st.u[1] = f2bf(d * a[1]);
    st.u[2] = f2bf(d * a[2]); st.u[3] = f2bf(d * a[3]);
    st.u[4] = f2bf(d * a[4]); st.u[5] = f2bf(d * a[5]);
    st.u[6] = f2bf(d * a[6]); st.u[7] = f2bf(d * a[7]);
    *(short8*)(&Lb[tn][lane * 8]) = st.v;
    __syncthreads();

    // transpose-read and store one coalesced 16B fragment chunk per thread
    const int nt = t >> 5, idx = t & 31;
    const int a_rel = (idx >> 4) & 1, fb = (idx >> 3) & 1, f7 = idx & 7;
    const int feat = nt * 16 + fb * 8 + f7;
    const int nl = a_rel * 8;
    uint4 o;
    o.x = (unsigned)Lb[nl + 0][feat] | ((unsigned)Lb[nl + 1][feat] << 16);
    o.y = (unsigned)Lb[nl + 2][feat] | ((unsigned)Lb[nl + 3][feat] << 16);
    o.z = (unsigned)Lb[nl + 4][feat] | ((unsigned)Lb[nl + 5][feat] << 16);
    o.w = (unsigned)Lb[nl + 6][feat] | ((unsigned)Lb[nl + 7][feat] << 16);
    size_t base = (size_t)(b >> 1) * 4096 + (size_t)nt * 512
                + (size_t)((b & 1) * 2 + a_rel) * 128 + (size_t)fb * 64 + (size_t)f7 * 8;
    *(uint4*)(Bsw + base) = o;
}

// ---------------- pool GEMM: P += T[64 x NNP] @ Bsw[NNP x 128] -------------
// (dinv folded into Bsw rows.) split-K, b128 fragment loads, no atomics.
__global__ __launch_bounds__(256) void k_pool_gemm(const float* __restrict__ T,
                                                   const ushort* __restrict__ Bsw,
                                                   float* __restrict__ partial) {
    const int t = threadIdx.x;
    const int wave = t >> 6, lane = t & 63;
    const int m = lane & 15, quad = lane >> 4;
    const int g = wave * 16 + m;
    const int k0 = blockIdx.x * KCH;

    float4v acc[8];
#pragma unroll
    for (int nt = 0; nt < 8; ++nt) acc[nt] = (float4v){0.f, 0.f, 0.f, 0.f};

#pragma unroll
    for (int s = 0; s < KCH / 32; ++s) {
        const int kb = k0 + s * 32 + quad * 8;
        const float* ap = T + (size_t)g * NNP + kb;
        float4 a0 = *(const float4*)ap;
        float4 a1 = *(const float4*)(ap + 4);
        union { short8 v; ushort u[8]; } af;
        af.u[0] = f2bf(a0.x); af.u[1] = f2bf(a0.y);
        af.u[2] = f2bf(a0.z); af.u[3] = f2bf(a0.w);
        af.u[4] = f2bf(a1.x); af.u[5] = f2bf(a1.y);
        af.u[6] = f2bf(a1.z); af.u[7] = f2bf(a1.w);

        const int t32 = (k0 >> 5) + s;
        const ushort* bb = Bsw + (size_t)t32 * 4096 + (size_t)lane * 8;
#pragma unroll
        for (int nt = 0; nt < 8; ++nt) {
            short8 bv = *(const short8*)(bb + nt * 512);
            acc[nt] = __builtin_amdgcn_mfma_f32_16x16x32_bf16(af.v, bv, acc[nt], 0, 0, 0);
        }
    }

    float* dst = partial + (size_t)blockIdx.x * (NG * DIM);
#pragma unroll
    for (int reg = 0; reg < 4; ++reg) {
        int gg = wave * 16 + quad * 4 + reg;
#pragma unroll
        for (int nt = 0; nt < 8; ++nt)
            dst[gg * DIM + nt * 16 + m] = acc[nt][reg];
    }
}

// ------- parallel split-K reduce: P[elem] += sum of 49 partials ------------
// 65536 threads (256 blocks): 8 chunks x 8192 elems, coalesced, 8-way atomics.
__global__ __launch_bounds__(256) void k_red(const float* __restrict__ partial,
                                             float* __restrict__ P) {
    int tid = blockIdx.x * 256 + threadIdx.x;
    int elem = tid & 8191, h = tid >> 13;       // h = 0..7, 49 partials each
    const float* pp = partial + (size_t)h * 49 * (NG * DIM) + elem;
    float s = 0.f;
#pragma unroll
    for (int i = 0; i < 49; ++i) s += pp[(size_t)i * (NG * DIM)];
    atomicAdd(&P[elem], s);
}

// ------- pooled = (P@W2)/cnt + b2; logits = pooled @ Wlin + blin -----------
__global__ __launch_bounds__(128) void k_final(const float* __restrict__ P,
                                               const float* __restrict__ W2,
                                               const float* __restrict__ b2,
                                               const float* __restrict__ Wlin,
                                               const float* __restrict__ blin,
                                               const int* __restrict__ batch,
                                               float* __restrict__ out) {
    const int g = blockIdx.x;
    const int t = threadIdx.x;
    int start;
    { int a = 0, bb = NN; while (a < bb) { int mm = (a + bb) >> 1; if (batch[mm] < g) a = mm + 1; else bb = mm; } start = a; }
    int endp;
    { int a = 0, bb = NN; while (a < bb) { int mm = (a + bb) >> 1; if (batch[mm] < g + 1) a = mm + 1; else bb = mm; } endp = a; }
    const int cnt = endp - start;

    __shared__ float Pl[DIM];
    __shared__ float pooled[DIM];
    Pl[t] = P[g * DIM + t];
    __syncthreads();
    float acc = 0.f;
    for (int k = 0; k < DIM; ++k) acc += Pl[k] * W2[k * DIM + t];   // fp32 W2
    pooled[t] = (cnt > 0) ? (acc / (float)cnt + b2[t]) : 0.f;
    __syncthreads();
    if (t < NCLS) {
        float s2 = blin[t];
        for (int k = 0; k < DIM; ++k) s2 += pooled[k] * Wlin[k * NCLS + t];
        out[g * NCLS + t] = s2;
    }
}

extern "C" void kernel_launch(void* const* d_in, const int* in_sizes, int n_in,
                              void* d_out, int out_size, void* d_ws, size_t ws_size,
                              hipStream_t stream) {
    const float* x    = (const float*)d_in[0];
    const float* W1   = (const float*)d_in[1];
    const float* b1   = (const float*)d_in[2];
    const float* W2   = (const float*)d_in[3];
    const float* b2   = (const float*)d_in[4];
    const float* Wlin = (const float*)d_in[5];
    const float* blin = (const float*)d_in[6];
    const int* eidx   = (const int*)d_in[7];   // [2, E] flat: rows then cols
    const int* batch  = (const int*)d_in[8];
    float* out = (float*)d_out;

    char* ws = (char*)d_ws;
    int*    cnt   = (int*)(ws + 0);             // NN ints (zeroed; ends as degree)
    ushort* Wsw   = (ushort*)(ws + 400704);     // 32768 B (W1 frags)
    ushort* ell   = (ushort*)(ws + 433472);     // NN*CAP ushort = 6.4 MB
    uchar*  Hs1   = (uchar*)(ws + 6833472);     // (NN+176)*DIM fp8 (row DUMMY = 0)
    float*  T     = (float*)(ws + 13256064);    // 64*NNP fp32 = 12845056 B
    ushort* Bsw   = (ushort*)(ws + 26101120);   // NNP*DIM bf16 frag layout = 12.8 MB
    float*  partial=(float*)(ws + 38946176);    // KBLK*NG*DIM fp32 = 12.8 MB
    float*  P     = (float*)(ws + 51791232);    // 64*DIM fp32 = 32 KB

    const int* erow = eidx;
    const int* ecol = eidx + NE;

    // ---- structure build: zero/prep + ELL dummy prefill, then ELL fill ----
    k_init<<<SB + 64 + 784 + 12 + 1 + ELLFB, 256, 0, stream>>>(cnt, W1, Wsw, T,
                                                               Bsw, P, Hs1, ell);
    k_fill<<<E4B, 256, 0, stream>>>(erow, ecol, cnt, ell);

    const int gemm_grid = (NN + 63) / 64;            // 782
    const int node_grid = NN / 16;                   // 3125 (exact, 16 nodes/block)

    // layer 1: Hs1 = fp8(dinv*(x @ W1)); Bsw = frag(d*relu(dinv*agg+b1)); T built
    k_gemm_mfma<<<gemm_grid, 256, 0, stream>>>(x, Wsw, cnt, Hs1);
    k_gather_ell<<<node_grid, 256, 0, stream>>>(ell, cnt, batch, b1, Hs1, T, Bsw);

    // layer 2 + pool, fully commuted: P = T @ Bsw (split-K partials + reduce)
    k_pool_gemm<<<KBLK, 256, 0, stream>>>(T, Bsw, partial);
    k_red<<<256, 256, 0, stream>>>(partial, P);

    // P@W2 (fp32) + /cnt + b2 + Wlin head
    k_final<<<NG, 128, 0, stream>>>(P, W2, b2, Wlin, blin, batch, out);
}